// Round 2
// baseline (487.357 us; speedup 1.0000x reference)
//
#include <hip/hip_runtime.h>
#include <hip/hip_bf16.h>
#include <stdint.h>

typedef __attribute__((ext_vector_type(8))) short s8v;
typedef __attribute__((ext_vector_type(4))) float f32x4;

__device__ __forceinline__ unsigned short f2bf(float f) {
  unsigned u = __builtin_bit_cast(unsigned, f);
  u += 0x7fffu + ((u >> 16) & 1u);
  return (unsigned short)(u >> 16);
}

__device__ __forceinline__ void gl16(const void* g, void* l) {
  __builtin_amdgcn_global_load_lds(
      (const __attribute__((address_space(1))) unsigned int*)g,
      (__attribute__((address_space(3))) unsigned int*)l,
      16, 0, 0);
}

// ---------------- prep kernels ----------------

__global__ void cast_bf16_k(const float* __restrict__ s, unsigned short* __restrict__ d, int n4) {
  int i = blockIdx.x * blockDim.x + threadIdx.x;
  if (i < n4) {
    float4 v = reinterpret_cast<const float4*>(s)[i];
    ushort4 o;
    o.x = f2bf(v.x); o.y = f2bf(v.y); o.z = f2bf(v.z); o.w = f2bf(v.w);
    reinterpret_cast<ushort4*>(d)[i] = o;
  }
}

// Build dense conv matrix Mt [3712 rows (conv outputs, padded)][256 cols (c*16+h*4+w)] bf16
// plus per-output bias cbias[3712].
__global__ void prep_conv(
    const float* w0, const float* w1, const float* w2, const float* w3,
    const float* w4, const float* w5, const float* w6,
    const float* b0, const float* b1, const float* b2, const float* b3,
    const float* b4, const float* b5, const float* b6,
    unsigned short* __restrict__ Mt, float* __restrict__ cbias)
{
  int n = blockIdx.x * blockDim.x + threadIdx.x;
  if (n >= 3712) return;
  unsigned short* row = Mt + n * 256;
  for (int i = 0; i < 256; ++i) row[i] = 0;
  if (n >= 3648) { cbias[n] = 0.f; return; }
  const int khs[7] = {1,2,1,3,1,4,2};
  const int kws[7] = {2,1,3,1,4,1,2};
  const int cs[8]  = {0,768,1536,2048,2560,2816,3072,3648};
  const float* ws[7] = {w0,w1,w2,w3,w4,w5,w6};
  const float* bs[7] = {b0,b1,b2,b3,b4,b5,b6};
  int k = 6;
  while (n < cs[k]) --k;
  const int kh = khs[k], kw = kws[k];
  const int ow = 5 - kw, np = (5 - kh) * ow;
  const int r = n - cs[k];
  const int och = r / np, p = r % np;
  const int oi = p / ow, oj = p % ow;
  const float* w = ws[k];
  cbias[n] = bs[k][och];
  for (int c = 0; c < 16; ++c)
    for (int dh = 0; dh < kh; ++dh)
      for (int dw = 0; dw < kw; ++dw)
        row[c * 16 + (oi + dh) * 4 + (oj + dw)] =
            f2bf(w[((och * 16 + c) * kh + dh) * kw + dw]);
}

// fw0 [512][3648] f32 -> fw0b [512][3712] bf16 (zero-padded K)
__global__ void prep_fw0(const float* __restrict__ fw0, unsigned short* __restrict__ outp) {
  int idx = blockIdx.x * 256 + threadIdx.x;  // 512*3712 total
  int nrow = idx / 3712;
  int k = idx - nrow * 3712;
  outp[idx] = (k < 3648) ? f2bf(fw0[nrow * 3648 + k]) : (unsigned short)0;
}

// ---------------- GEMM: C[M][N] = relu(A[M][K] * Bt[N][K]^T + bias), bf16 out ----------------
// 128x128 tile, BK=64, 4 waves (2x2), m97-structure with global_load_lds.
// Bijective XCD-aware swizzle (works for any gridDim).
__global__ __launch_bounds__(256) void gemm_bt_relu(
    const unsigned short* __restrict__ A, int lda,
    const unsigned short* __restrict__ Bt, int ldb,
    const float* __restrict__ bias,
    unsigned short* __restrict__ C, int ldc,
    int K, int ntn)
{
  __shared__ unsigned short As[128 * 64];
  __shared__ unsigned short Bs[128 * 64];
  const int tid = threadIdx.x;
  const int lane = tid & 63;
  const int wave = tid >> 6;
  const int wm = wave >> 1, wn = wave & 1;

  // bijective XCD swizzle: consecutive wgid (same XCD) share an M-panel
  const int nwg = gridDim.x;
  const int xcd = blockIdx.x & 7;
  const int idx = blockIdx.x >> 3;
  const int q = nwg >> 3, r = nwg & 7;
  const int wgid = (xcd < r ? xcd * (q + 1) : r * (q + 1) + (xcd - r) * q) + idx;
  const int mt = wgid / ntn;
  const int nt = wgid - mt * ntn;
  const int m0 = mt * 128, n0 = nt * 128;

  f32x4 acc[4][4] = {};

  const unsigned short* Ag = A + (size_t)(m0 + (lane >> 3)) * lda + (lane & 7) * 8;
  const unsigned short* Bg = Bt + (size_t)(n0 + (lane >> 3)) * ldb + (lane & 7) * 8;
  char* Asb = (char*)As + wave * 4096 + lane * 16;
  char* Bsb = (char*)Bs + wave * 4096 + lane * 16;

  for (int k0 = 0; k0 < K; k0 += 64) {
#pragma unroll
    for (int i = 0; i < 4; ++i) {
      const int inst = wave * 4 + i;
      gl16(Ag + (size_t)(inst * 8) * lda + k0, Asb + i * 1024);
      gl16(Bg + (size_t)(inst * 8) * ldb + k0, Bsb + i * 1024);
    }
    __syncthreads();
    const int arow = wm * 64 + (lane & 15);
    const int brow = wn * 64 + (lane & 15);
    const int kc = (lane >> 4) * 8;
    s8v af[4][2], bfv[4][2];
#pragma unroll
    for (int mi = 0; mi < 4; ++mi)
#pragma unroll
      for (int kk = 0; kk < 2; ++kk)
        af[mi][kk] = *(const s8v*)(As + (arow + mi * 16) * 64 + kk * 32 + kc);
#pragma unroll
    for (int ni = 0; ni < 4; ++ni)
#pragma unroll
      for (int kk = 0; kk < 2; ++kk)
        bfv[ni][kk] = *(const s8v*)(Bs + (brow + ni * 16) * 64 + kk * 32 + kc);
#pragma unroll
    for (int kk = 0; kk < 2; ++kk)
#pragma unroll
      for (int mi = 0; mi < 4; ++mi)
#pragma unroll
        for (int ni = 0; ni < 4; ++ni)
          acc[mi][ni] = __builtin_amdgcn_mfma_f32_16x16x32_bf16(
              af[mi][kk], bfv[ni][kk], acc[mi][ni], 0, 0, 0);
    __syncthreads();
  }

#pragma unroll
  for (int ni = 0; ni < 4; ++ni) {
    const int col = n0 + wn * 64 + ni * 16 + (lane & 15);
    const float bv = bias[col];
#pragma unroll
    for (int mi = 0; mi < 4; ++mi) {
      const int row = m0 + wm * 64 + mi * 16 + (lane >> 4) * 4;
#pragma unroll
      for (int r2 = 0; r2 < 4; ++r2) {
        float v = acc[mi][ni][r2] + bv;
        v = v > 0.f ? v : 0.f;
        C[(size_t)(row + r2) * ldc + col] = f2bf(v);
      }
    }
  }
}

// ---------------- FC2 (MFMA) + FC3 (fp32 VALU) fused ----------------
// 64-row tiles. h1[CH][512] bf16 -> h2 [64][128] f32 in LDS -> out [64][4] f32.
__global__ __launch_bounds__(256) void fc23(
    const unsigned short* __restrict__ h1,
    const unsigned short* __restrict__ fw1b,
    const float* __restrict__ fb1,
    const float* __restrict__ fw2,
    const float* __restrict__ fb2,
    float* __restrict__ out)
{
  __shared__ unsigned short As[64 * 64];
  __shared__ unsigned short Bs[128 * 64];
  __shared__ float h2[64][129];
  const int tid = threadIdx.x;
  const int lane = tid & 63;
  const int wave = tid >> 6;
  const int wm = wave >> 1, wn = wave & 1;
  const int m0 = blockIdx.x * 64;

  f32x4 acc[2][4] = {};

  const unsigned short* Ag = h1 + (size_t)(m0 + (lane >> 3)) * 512 + (lane & 7) * 8;
  const unsigned short* Bg = fw1b + (size_t)(lane >> 3) * 512 + (lane & 7) * 8;
  char* Asb = (char*)As + wave * 2048 + lane * 16;
  char* Bsb = (char*)Bs + wave * 4096 + lane * 16;

  for (int k0 = 0; k0 < 512; k0 += 64) {
#pragma unroll
    for (int i = 0; i < 2; ++i)
      gl16(Ag + (size_t)((wave * 2 + i) * 8) * 512 + k0, Asb + i * 1024);
#pragma unroll
    for (int i = 0; i < 4; ++i)
      gl16(Bg + (size_t)((wave * 4 + i) * 8) * 512 + k0, Bsb + i * 1024);
    __syncthreads();
    const int arow = wm * 32 + (lane & 15);
    const int brow = wn * 64 + (lane & 15);
    const int kc = (lane >> 4) * 8;
    s8v af[2][2], bfv[4][2];
#pragma unroll
    for (int mi = 0; mi < 2; ++mi)
#pragma unroll
      for (int kk = 0; kk < 2; ++kk)
        af[mi][kk] = *(const s8v*)(As + (arow + mi * 16) * 64 + kk * 32 + kc);
#pragma unroll
    for (int ni = 0; ni < 4; ++ni)
#pragma unroll
      for (int kk = 0; kk < 2; ++kk)
        bfv[ni][kk] = *(const s8v*)(Bs + (brow + ni * 16) * 64 + kk * 32 + kc);
#pragma unroll
    for (int kk = 0; kk < 2; ++kk)
#pragma unroll
      for (int mi = 0; mi < 2; ++mi)
#pragma unroll
        for (int ni = 0; ni < 4; ++ni)
          acc[mi][ni] = __builtin_amdgcn_mfma_f32_16x16x32_bf16(
              af[mi][kk], bfv[ni][kk], acc[mi][ni], 0, 0, 0);
    __syncthreads();
  }

#pragma unroll
  for (int ni = 0; ni < 4; ++ni) {
    const int col = wn * 64 + ni * 16 + (lane & 15);
    const float bv = fb1[col];
#pragma unroll
    for (int mi = 0; mi < 2; ++mi) {
      const int rl = wm * 32 + mi * 16 + (lane >> 4) * 4;
#pragma unroll
      for (int r = 0; r < 4; ++r) {
        float v = acc[mi][ni][r] + bv;
        h2[rl + r][col] = v > 0.f ? v : 0.f;
      }
    }
  }
  __syncthreads();

  // FC3 in fp32: one (row, j) per thread; coalesced f32 store.
  const int r = tid >> 2, j = tid & 3;
  const float* w = fw2 + j * 128;
  float dot = fb2[j];
#pragma unroll 8
  for (int c = 0; c < 128; ++c) dot += h2[r][c] * w[c];
  out[(size_t)(m0 + r) * 4 + j] = dot;
}

// ---------------- launch ----------------

extern "C" void kernel_launch(void* const* d_in, const int* in_sizes, int n_in,
                              void* d_out, int out_size, void* d_ws, size_t ws_size,
                              hipStream_t stream) {
  const float* x = (const float*)d_in[0];
  const float* w[7];
  const float* b[7];
  for (int i = 0; i < 7; ++i) {
    w[i] = (const float*)d_in[1 + 2 * i];
    b[i] = (const float*)d_in[2 + 2 * i];
  }
  const float* fw0 = (const float*)d_in[15];
  const float* fb0 = (const float*)d_in[16];
  const float* fw1 = (const float*)d_in[17];
  const float* fb1 = (const float*)d_in[18];
  const float* fw2 = (const float*)d_in[19];
  const float* fb2 = (const float*)d_in[20];

  auto a256 = [](size_t v) { return (v + 255) & ~(size_t)255; };
  const size_t persistent =
      a256((size_t)3712 * 256 * 2) +  // Mt
      a256((size_t)3712 * 4) +        // cbias
      a256((size_t)512 * 3712 * 2) +  // fw0b
      a256((size_t)128 * 512 * 2);    // fw1b

  // pick largest chunk CH (rows of B) whose buffers fit in ws_size
  int CH = 0;
  for (int c = 32768; c >= 128; c >>= 1) {
    size_t need = persistent + a256((size_t)c * 256 * 2)    // xb chunk
                             + a256((size_t)c * 3712 * 2)   // comb chunk
                             + a256((size_t)c * 512 * 2);   // h1 chunk
    if (need <= ws_size) { CH = c; break; }
  }
  if (!CH) return;  // ws < ~7 MB: cannot run (diagnostic: absmax == ref absmax)

  char* ws = (char*)d_ws;
  size_t off = 0;
  auto alloc = [&](size_t bytes) {
    void* p = ws + off;
    off += (bytes + 255) & ~(size_t)255;
    return p;
  };
  unsigned short* Mt   = (unsigned short*)alloc((size_t)3712 * 256 * 2);
  float*          cb   = (float*)alloc((size_t)3712 * 4);
  unsigned short* fw0b = (unsigned short*)alloc((size_t)512 * 3712 * 2);
  unsigned short* fw1b = (unsigned short*)alloc((size_t)128 * 512 * 2);
  unsigned short* xb   = (unsigned short*)alloc((size_t)CH * 256 * 2);
  unsigned short* comb = (unsigned short*)alloc((size_t)CH * 3712 * 2);
  unsigned short* h1   = (unsigned short*)alloc((size_t)CH * 512 * 2);

  // one-time preps
  cast_bf16_k<<<64, 256, 0, stream>>>(fw1, fw1b, 16384);
  prep_conv<<<15, 256, 0, stream>>>(w[0], w[1], w[2], w[3], w[4], w[5], w[6],
                                    b[0], b[1], b[2], b[3], b[4], b[5], b[6], Mt, cb);
  prep_fw0<<<7424, 256, 0, stream>>>(fw0, fw0b);

  const int nchunks = 32768 / CH;
  const int mtiles = CH / 128;  // >= 1
  for (int c = 0; c < nchunks; ++c) {
    const size_t row0 = (size_t)c * CH;
    // cast x chunk -> bf16
    cast_bf16_k<<<(CH * 64 + 255) / 256, 256, 0, stream>>>(
        x + row0 * 256, xb, CH * 64);
    // conv-as-GEMM: [CH][256] x [3712][256]^T -> comb bf16 [CH][3712]
    gemm_bt_relu<<<mtiles * 29, 256, 0, stream>>>(
        xb, 256, Mt, 256, cb, comb, 3712, 256, 29);
    // FC1: [CH][3712] x [512][3712]^T -> h1 bf16 [CH][512]
    gemm_bt_relu<<<mtiles * 4, 256, 0, stream>>>(
        comb, 3712, fw0b, 3712, fb0, h1, 512, 3712, 4);
    // FC2 + FC3 -> out rows [row0, row0+CH)
    fc23<<<CH / 64, 256, 0, stream>>>(
        h1, fw1b, fb1, fw2, fb2, (float*)d_out + row0 * 4);
  }
}